// Round 2
// baseline (7903.643 us; speedup 1.0000x reference)
//
#include <hip/hip_runtime.h>

#define T_STEPS 512
#define BATCH   1024
#define IN_DIM  64
#define HID     256
#define OUT_DIM 32

typedef _Float16 f16;
typedef __attribute__((ext_vector_type(8))) _Float16 f16x8;
typedef __attribute__((ext_vector_type(4))) float f32x4;
typedef unsigned int u32;

// d_ws layout (f16 element offsets). Prep kernel fills every element each call
// (ws is re-poisoned to 0xAA before every timed launch).
#define WZH 0
#define WZL 65536
#define WTH 131072
#define WTL 196608
#define WXH 262144
#define WXL 278528
#define WOH 294912
// total 303104 f16 = 606208 bytes

// LDS byte offsets. Activation planes are [2 buf][8 rows][K] f16, XOR-swizzled
// (byte ^= (row&7)<<4) within each row for conflict-free ds_read_b128.
// Row slots: n=0..3 real part of batch rows 0..3, n=4..7 imag part.
#define TH_HI 0        // tanh hi   [2][8][256] : 8192
#define TH_LO 8192     // tanh lo
#define TA_HI 16384    // zmod hi
#define TA_LO 24576    // zmod lo
#define X_HI  32768    // x hi      [2][8][64]  : 2048 (rows 4..7 stay zero)
#define X_LO  34816    // x lo
#define O_S   36864    // z_r_new (single f16; y-path does not feed back)
#define WOUT  45056    // W_out f16 [32][256] swizzled : 16384
#define LDS_BYTES 61440
#define LDS_ZERO_WORDS 11264   // zero bytes [0, 45056)

#define MFMA(a,b,c) __builtin_amdgcn_mfma_f32_16x16x32_f16((a),(b),(c),0,0,0)

__device__ __forceinline__ u32 pkh(f16 a, f16 b) {
  return (u32)__builtin_bit_cast(unsigned short, a) |
         ((u32)__builtin_bit_cast(unsigned short, b) << 16);
}
__device__ __forceinline__ void split_pk(float a, float b, u32& hi_w, u32& lo_w) {
  const f16 ah = (f16)a, bh = (f16)b;
  const f16 al = (f16)(a - (float)ah), bl = (f16)(b - (float)bh);
  hi_w = pkh(ah, bh); lo_w = pkh(al, bl);
}

// Decompose fp32 weights into f16 hi + f16 lo (exact Ootomo split: residual
// after hi is exactly representable in fp32; lo captures it to ~6e-8 rel).
__global__ void prep_kernel(const float* __restrict__ Wz, const float* __restrict__ Wx,
                            const float* __restrict__ Wo, const float* __restrict__ Wt,
                            f16* __restrict__ ws) {
  const int idx = blockIdx.x * 256 + threadIdx.x;   // 0..65535
  {
    float w = Wz[idx]; f16 h = (f16)w;
    ws[WZH + idx] = h; ws[WZL + idx] = (f16)(w - (float)h);
    w = Wt[idx]; h = (f16)w;
    ws[WTH + idx] = h; ws[WTL + idx] = (f16)(w - (float)h);
  }
  if (idx < 16384) {
    float w = Wx[idx]; f16 h = (f16)w;
    ws[WXH + idx] = h; ws[WXL + idx] = (f16)(w - (float)h);
  }
  if (idx < 8192) ws[WOH + idx] = (f16)Wo[idx];
}

// 256 blocks x 512 threads (8 waves). Block owns 4 batch rows for all T steps.
// Wave w owns hidden rows [32w, 32w+32). Feedback GEMMs are fp32-grade:
// acc = Whi*t_hi + Whi*t_lo + Wlo*t_hi  (f16 hi/lo pairs, fp32 MFMA accum).
__global__ __launch_bounds__(512, 2)
void lnn_kernel(const float* __restrict__ xg, const f16* __restrict__ ws,
                const float* __restrict__ bz, const float* __restrict__ bx,
                const float* __restrict__ bo, float* __restrict__ y)
{
  __shared__ __align__(16) char smem[LDS_BYTES];
  const int tid   = threadIdx.x;
  const int wave  = tid >> 6;
  const int lane  = tid & 63;
  const int n     = lane & 15;   // B/D column slot (also A-frag M row index)
  const int kg    = lane >> 4;   // k-group
  const int nr8   = n & 7;
  const int swzn  = nr8 << 4;
  const int rbase = blockIdx.x * 4;
  const int wbase = wave * 32;

  // ---- persistent hi-weight A-fragments (m = lane&15, k = kt*32 + kg*8 + j) ----
  f16x8 wzh[2][8], wth[2][8], wxh[2][2];
  const int row0 = wbase + n, row1 = wbase + 16 + n;
#pragma unroll
  for (int kt = 0; kt < 8; ++kt) {
    wzh[0][kt] = *(const f16x8*)(ws + WZH + row0*HID + kt*32 + kg*8);
    wzh[1][kt] = *(const f16x8*)(ws + WZH + row1*HID + kt*32 + kg*8);
    wth[0][kt] = *(const f16x8*)(ws + WTH + row0*HID + kt*32 + kg*8);
    wth[1][kt] = *(const f16x8*)(ws + WTH + row1*HID + kt*32 + kg*8);
  }
#pragma unroll
  for (int kt = 0; kt < 2; ++kt) {
    wxh[0][kt] = *(const f16x8*)(ws + WXH + row0*IN_DIM + kt*32 + kg*8);
    wxh[1][kt] = *(const f16x8*)(ws + WXH + row1*IN_DIM + kt*32 + kg*8);
  }
  // lo-weight stream base pointers (re-read from L2 every step)
  const f16* pzl0 = ws + WZL + row0*HID + kg*8;
  const f16* pzl1 = ws + WZL + row1*HID + kg*8;
  const f16* ptl0 = ws + WTL + row0*HID + kg*8;
  const f16* ptl1 = ws + WTL + row1*HID + kg*8;
  const f16* pxl0 = ws + WXL + row0*IN_DIM + kg*8;
  const f16* pxl1 = ws + WXL + row1*IN_DIM + kg*8;

  // per-lane bias: b_z for all, +b_x only for real-part columns (n<4)
  float bias_ri[2][4];
#pragma unroll
  for (int mt = 0; mt < 2; ++mt)
#pragma unroll
    for (int r = 0; r < 4; ++r) {
      const int h = wbase + mt*16 + kg*4 + r;
      bias_ri[mt][r] = bz[h] + ((n < 4) ? bx[h] : 0.f);
    }
  float bo_reg[4] = {0.f, 0.f, 0.f, 0.f};
  if (wave < 2)
#pragma unroll
    for (int r = 0; r < 4; ++r) bo_reg[r] = bo[wave*16 + kg*4 + r];

  // ---- LDS init: zero act planes, stage W_out f16 (swizzled) ----
  for (int idx = tid; idx < LDS_ZERO_WORDS; idx += 512)
    ((u32*)smem)[idx] = 0u;
  {
    const int r = tid >> 4;            // 0..31
    const int c0 = (tid & 15) * 16;    // 16 cols per thread
    const int swzr = (r & 7) << 4;
    const f16* wo = ws + WOH + r*HID + c0;
#pragma unroll
    for (int p2 = 0; p2 < 16; p2 += 2)
      *(u32*)(smem + WOUT + r*512 + (((c0 + p2)*2) ^ swzr)) = pkh(wo[p2], wo[p2+1]);
  }
  __syncthreads();
  // x(t=0) into x planes buf 0 (waves 6,7: 128 threads x float2, coalesced)
  if (tid >= 384) {
    const int idx = tid - 384;
    const float2 v = *(const float2*)(xg + rbase*IN_DIM + idx*2);
    const int xr = idx >> 5, k0 = (idx & 31) * 2, swzx = (xr & 7) << 4;
    u32 vh, vl; split_pk(v.x, v.y, vh, vl);
    *(u32*)(smem + X_HI + xr*128 + ((k0*2) ^ swzx)) = vh;
    *(u32*)(smem + X_LO + xr*128 + ((k0*2) ^ swzx)) = vl;
  }

  // state in D-layout: lane holds z (real if n<4, imag if 4<=n<8) for
  // batch slot (n&3), h = wbase + mt*16 + kg*4 + r. fp32, never leaves regs.
  float zst[2][4] = {{0.f,0.f,0.f,0.f},{0.f,0.f,0.f,0.f}};
  const f32x4 zero4 = {0.f, 0.f, 0.f, 0.f};

#pragma unroll 2
  for (int i = 0; i < T_STEPS; ++i) {
    __syncthreads();                 // act[cur] complete; also fences lo-loads per iter
    const int cur = i & 1, nxt = cur ^ 1;

    // prefetch x(i+1) early (consumed after EW)
    float2 xv = {0.f, 0.f};
    if (tid >= 384 && i + 1 < T_STEPS) {
      const int idx = tid - 384;
      xv = *(const float2*)(xg + ((i+1)*BATCH + rbase)*IN_DIM + idx*2);
    }

    // ---- GEMM1 (3-term fp32-grade): acc_z = Wx*x + Wz*tanh ; acc_tau = Wtau*zmod ----
    f32x4 accz0 = zero4, accz1 = zero4, acct0 = zero4, acct1 = zero4;
#pragma unroll
    for (int kt = 0; kt < 2; ++kt) {
      const int cbx = (kt*64 + kg*16) ^ swzn;
      const f16x8 bh = *(const f16x8*)(smem + X_HI + cur*1024 + nr8*128 + cbx);
      const f16x8 bl = *(const f16x8*)(smem + X_LO + cur*1024 + nr8*128 + cbx);
      const f16x8 l0 = *(const f16x8*)(pxl0 + kt*32);
      const f16x8 l1 = *(const f16x8*)(pxl1 + kt*32);
      accz0 = MFMA(wxh[0][kt], bh, accz0); accz0 = MFMA(wxh[0][kt], bl, accz0);
      accz0 = MFMA(l0, bh, accz0);
      accz1 = MFMA(wxh[1][kt], bh, accz1); accz1 = MFMA(wxh[1][kt], bl, accz1);
      accz1 = MFMA(l1, bh, accz1);
    }
#pragma unroll
    for (int kt = 0; kt < 8; ++kt) {
      const int cb = (kt*64 + kg*16) ^ swzn;
      const f16x8 bh = *(const f16x8*)(smem + TH_HI + cur*4096 + nr8*512 + cb);
      const f16x8 bl = *(const f16x8*)(smem + TH_LO + cur*4096 + nr8*512 + cb);
      const f16x8 ch = *(const f16x8*)(smem + TA_HI + cur*4096 + nr8*512 + cb);
      const f16x8 cl = *(const f16x8*)(smem + TA_LO + cur*4096 + nr8*512 + cb);
      const f16x8 zl0 = *(const f16x8*)(pzl0 + kt*32);
      const f16x8 zl1 = *(const f16x8*)(pzl1 + kt*32);
      const f16x8 tl0 = *(const f16x8*)(ptl0 + kt*32);
      const f16x8 tl1 = *(const f16x8*)(ptl1 + kt*32);
      accz0 = MFMA(wzh[0][kt], bh, accz0); accz0 = MFMA(wzh[0][kt], bl, accz0);
      accz0 = MFMA(zl0, bh, accz0);
      accz1 = MFMA(wzh[1][kt], bh, accz1); accz1 = MFMA(wzh[1][kt], bl, accz1);
      accz1 = MFMA(zl1, bh, accz1);
      acct0 = MFMA(wth[0][kt], ch, acct0); acct0 = MFMA(wth[0][kt], cl, acct0);
      acct0 = MFMA(tl0, ch, acct0);
      acct1 = MFMA(wth[1][kt], ch, acct1); acct1 = MFMA(wth[1][kt], cl, acct1);
      acct1 = MFMA(tl1, ch, acct1);
    }

    // ---- GEMM2 (pipelined): y(t=i-1) = z_r_new(i-1) @ W_out, waves 0/1 ----
    if (wave < 2 && i > 0) {
      f32x4 acco = zero4;
#pragma unroll
      for (int kt = 0; kt < 8; ++kt) {
        const int cb = (kt*64 + kg*16) ^ swzn;
        const f16x8 b = *(const f16x8*)(smem + O_S + cur*4096 + nr8*512 + cb);
        const f16x8 a = *(const f16x8*)(smem + WOUT + (wave*16 + n)*512 + cb);
        acco = MFMA(a, b, acco);
      }
      if (n < 4) {
        float* yp = y + ((i-1)*BATCH + rbase + n)*OUT_DIM + wave*16 + kg*4;
#pragma unroll
        for (int r = 0; r < 4; ++r) yp[r] = acco[r] + bo_reg[r];
      }
    }

    // ---- elementwise state update (precise fp32) + write act[nxt] pairs ----
#pragma unroll
    for (int mt = 0; mt < 2; ++mt) {
      const f32x4 az = (mt == 0) ? accz0 : accz1;
      const f32x4 at = (mt == 0) ? acct0 : acct1;
      f16 thh[4], thl[4], zmh[4], zml[4], zns[4];
#pragma unroll
      for (int r = 0; r < 4; ++r) {
        const float wtv = az[r] + bias_ri[mt][r];
        const float z   = zst[mt][r];
        const float dz  = wtv - z;                      // -z + W tanh (+Ux+bx if real)
        const float sg  = 1.0f / (1.0f + expf(-at[r]));
        const float tau = sg + 1e-6f;
        float dzc = dz / tau;
        dzc = fminf(fmaxf(dzc, -10.0f), 10.0f);
        const float zn = z + 0.1f * dzc;
        zst[mt][r] = zn;
        const float t   = tanhf(zn);
        const float zsq = zn * zn;
        const float psq = __shfl_xor(zsq, 4, 64);       // partner (r<->i) |z|^2
        const float zmv = sqrtf(zsq + psq);
        thh[r] = (f16)t;   thl[r] = (f16)(t   - (float)thh[r]);
        zmh[r] = (f16)zmv; zml[r] = (f16)(zmv - (float)zmh[r]);
        zns[r] = (f16)zn;
      }
      if (n < 8) {                                      // real+imag columns write
        const int hb = (wbase + mt*16 + kg*4) * 2;
#pragma unroll
        for (int rp = 0; rp < 4; rp += 2) {
          const int cb = (hb + rp*2) ^ swzn;
          const int ro = nxt*4096 + nr8*512 + cb;
          *(u32*)(smem + TH_HI + ro) = pkh(thh[rp], thh[rp+1]);
          *(u32*)(smem + TH_LO + ro) = pkh(thl[rp], thl[rp+1]);
          *(u32*)(smem + TA_HI + ro) = pkh(zmh[rp], zmh[rp+1]);
          *(u32*)(smem + TA_LO + ro) = pkh(zml[rp], zml[rp+1]);
          *(u32*)(smem + O_S  + ro) = pkh(zns[rp], zns[rp+1]);
        }
      }
    }

    // write prefetched x(i+1) pairs
    if (tid >= 384 && i + 1 < T_STEPS) {
      const int idx = tid - 384;
      const int xr = idx >> 5, k0 = (idx & 31) * 2, swzx = (xr & 7) << 4;
      u32 vh, vl; split_pk(xv.x, xv.y, vh, vl);
      *(u32*)(smem + X_HI + nxt*1024 + xr*128 + ((k0*2) ^ swzx)) = vh;
      *(u32*)(smem + X_LO + nxt*1024 + xr*128 + ((k0*2) ^ swzx)) = vl;
    }
  }

  // ---- epilogue: y(T-1). EW at i=511 wrote O_S buffer ((511&1)^1)=0 ----
  __syncthreads();
  if (wave < 2) {
    f32x4 acco = zero4;
#pragma unroll
    for (int kt = 0; kt < 8; ++kt) {
      const int cb = (kt*64 + kg*16) ^ swzn;
      const f16x8 b = *(const f16x8*)(smem + O_S + 0*4096 + nr8*512 + cb);
      const f16x8 a = *(const f16x8*)(smem + WOUT + (wave*16 + n)*512 + cb);
      acco = MFMA(a, b, acco);
    }
    if (n < 4) {
      float* yp = y + ((T_STEPS-1)*BATCH + rbase + n)*OUT_DIM + wave*16 + kg*4;
#pragma unroll
      for (int r = 0; r < 4; ++r) yp[r] = acco[r] + bo_reg[r];
    }
  }
}

extern "C" void kernel_launch(void* const* d_in, const int* in_sizes, int n_in,
                              void* d_out, int out_size, void* d_ws, size_t ws_size,
                              hipStream_t stream) {
  const float* xg = (const float*)d_in[0];
  const float* Wz = (const float*)d_in[1];
  const float* Wx = (const float*)d_in[2];
  const float* Wo = (const float*)d_in[3];
  const float* Wt = (const float*)d_in[4];
  const float* bz = (const float*)d_in[5];
  const float* bx = (const float*)d_in[6];
  const float* bo = (const float*)d_in[7];
  f16* ws = (f16*)d_ws;
  prep_kernel<<<dim3(256), dim3(256), 0, stream>>>(Wz, Wx, Wo, Wt, ws);
  lnn_kernel<<<dim3(BATCH/4), dim3(512), 0, stream>>>(xg, ws, bz, bx, bo, (float*)d_out);
}